// Round 7
// baseline (275.425 us; speedup 1.0000x reference)
//
#include <hip/hip_runtime.h>
#include <cstdint>
#include <cstddef>

#define S_LEN 4096
#define HIDD 768
#define NH 12
#define FFD 3072

typedef float f32x4 __attribute__((ext_vector_type(4)));
typedef short s16x8 __attribute__((ext_vector_type(8)));
typedef short s16x4 __attribute__((ext_vector_type(4)));

__device__ __forceinline__ short f2bf(float f) {
  unsigned u = __float_as_uint(f);
  u += 0x7fffu + ((u >> 16) & 1u);
  return (short)(u >> 16);
}
__device__ __forceinline__ float bf2f(short s) {
  return __uint_as_float(((unsigned)(unsigned short)s) << 16);
}

// async global->LDS, 16B per lane; LDS dest is wave-uniform base + lane*16
__device__ __forceinline__ void gload16(const short* g, short* l) {
  __builtin_amdgcn_global_load_lds(
      (__attribute__((address_space(1))) void*)(void*)const_cast<short*>(g),
      (__attribute__((address_space(3))) void*)l, 16, 0, 0);
}

// ---------------- conversion: f32 -> bf16 (flat, vectorized) ----------------
__global__ void convx_k(const float* __restrict__ x, short* __restrict__ o) {
  size_t i = (size_t)blockIdx.x * 256 + threadIdx.x;
  float4 f = ((const float4*)x)[i];
  s16x4 v;
  v[0] = f2bf(f.x); v[1] = f2bf(f.y); v[2] = f2bf(f.z); v[3] = f2bf(f.w);
  ((s16x4*)o)[i] = v;
}

// ------------- weight transpose + convert: W[R][C] f32 -> Wt[C][R] bf16 -----
__global__ void wtrans_k(const float* __restrict__ Wq, const float* __restrict__ Wk,
                         const float* __restrict__ Wv, const float* __restrict__ Wd,
                         const float* __restrict__ Wf, const float* __restrict__ Wo,
                         short* __restrict__ oq, short* __restrict__ ok_,
                         short* __restrict__ ov, short* __restrict__ od,
                         short* __restrict__ of_, short* __restrict__ oo) {
  __shared__ float tl[64][65];
  int id = blockIdx.x;
  const float* in; short* out; int R, C, tr, tc;
  if (id < 576) {
    int wsel = id / 144; int t = id % 144; tr = t / 12; tc = t % 12; R = 768; C = 768;
    in = wsel == 0 ? Wq : wsel == 1 ? Wk : wsel == 2 ? Wv : Wd;
    out = wsel == 0 ? oq : wsel == 1 ? ok_ : wsel == 2 ? ov : od;
  } else if (id < 1152) {
    int t = id - 576; tr = t / 48; tc = t % 48; R = 768; C = 3072; in = Wf; out = of_;
  } else {
    int t = id - 1152; tr = t / 12; tc = t % 12; R = 3072; C = 768; in = Wo; out = oo;
  }
  int r0 = tr * 64, c0 = tc * 64;
  int tid = threadIdx.x;
  #pragma unroll
  for (int i = 0; i < 16; i++) {
    int idx = i * 256 + tid; int r = idx >> 6, cc = idx & 63;
    tl[r][cc] = in[(size_t)(r0 + r) * C + c0 + cc];
  }
  __syncthreads();
  #pragma unroll
  for (int i = 0; i < 16; i++) {
    int idx = i * 256 + tid; int cc = idx >> 6, rr = idx & 63;
    out[(size_t)(c0 + cc) * R + r0 + rr] = f2bf(tl[rr][cc]);
  }
}

// ---------------- v head-layout transpose: [bh][s][64] -> [bh][64][s] -------
__global__ void vtrans_k(const short* __restrict__ vh, short* __restrict__ vth) {
  __shared__ short tl[64][72];
  int s0 = blockIdx.x * 64; int bh = blockIdx.y;
  int tid = threadIdx.x;
  const short* base = vh + ((size_t)bh << 18);
  #pragma unroll
  for (int i = 0; i < 16; i++) {
    int idx = i * 256 + tid; int r = idx >> 6, cc = idx & 63;
    tl[r][cc] = base[(size_t)(s0 + r) * 64 + cc];
  }
  __syncthreads();
  short* ob = vth + ((size_t)bh << 18);
  #pragma unroll
  for (int i = 0; i < 16; i++) {
    int idx = i * 256 + tid; int dh = idx >> 6, s = idx & 63;
    ob[((size_t)dh << 12) + s0 + s] = tl[s][dh];
  }
}

// ================= 8-phase 256x256 GEMM (T2+T3+T4+T5) =======================
// C[M][N] = A[M][K]*Bt[N][K]^T. 512 thr = 8 waves (2M x 4N), per-wave 128x64.
// BK=64; LDS 2dbuf x ([256][64] A + [256][64] B) = 128 KB. Quadrant Z-order
// (0,0)->(0,1)->(1,1)->(1,0): A-quad frags reused across 2 phases, B-half
// frags held across the tile -> 24 ds_read_b128 / K-tile / wave.
// Staging: A-halves @ph0, B-halves @ph1 (4 gload16 each, inverse-swizzled
// source), drained by boundary vmcnt(0) ~2-3 phases later. setprio around
// MFMA clusters. EPI 0: fused QKV head-split; EPI 1: tanh-GELU bf16.
template <int QM, int QN>
__device__ __forceinline__ void mmac(f32x4 (&acc)[8][4], const s16x8 (&af)[4][2],
                                     const s16x8 (&bf)[2][2]) {
  #pragma unroll
  for (int ks = 0; ks < 2; ks++)
    #pragma unroll
    for (int mt = 0; mt < 4; mt++)
      #pragma unroll
      for (int nt = 0; nt < 2; nt++)
        acc[QM * 4 + mt][QN * 2 + nt] = __builtin_amdgcn_mfma_f32_16x16x32_bf16(
            af[mt][ks], bf[nt][ks], acc[QM * 4 + mt][QN * 2 + nt], 0, 0, 0);
}

template <int EPI>
__global__ void __launch_bounds__(512, 1) gemm8p(
    const short* __restrict__ A, const short* __restrict__ Bt,
    const float* __restrict__ bias, const float* __restrict__ bias1,
    const float* __restrict__ bias2, void* __restrict__ out, int N, int K,
    int MB) {
  extern __shared__ __align__(16) short sm[];
  constexpr int TSZ = 256 * 64;            // shorts per dbuf side
  short* Abase = sm;                       // [2][256][64]
  short* Bbase = sm + 2 * TSZ;             // [2][256][64]

  const int tid = threadIdx.x;
  const int lane = tid & 63;
  const int w = tid >> 6;
  const int wr = w >> 2, wc = w & 3;       // 2M x 4N wave grid
  const int lm = lane & 15, lk = lane >> 4;

  // XCD-bijective swizzle (m204), then m-major decomposition
  const int nwg = gridDim.x;
  const int bid = blockIdx.x;
  const int q = nwg >> 3, r = nwg & 7;
  const int xcd = bid & 7, idx = bid >> 3;
  const int wg = (xcd < r ? xcd * (q + 1) : r * (q + 1) + (xcd - r) * q) + idx;
  const int mb = wg % MB, nb = wg / MB;
  const int m0 = mb * 256, n0 = nb * 256;

  const int lr = lane >> 3;
  const int seg = (lane & 7) ^ lr;         // inverse-swizzled source segment

  f32x4 acc[8][4];
  #pragma unroll
  for (int i = 0; i < 8; i++)
    #pragma unroll
    for (int j = 0; j < 4; j++) { acc[i][j][0] = 0.f; acc[i][j][1] = 0.f; acc[i][j][2] = 0.f; acc[i][j][3] = 0.f; }

  const short* Ag = A + (size_t)(m0 + lr) * K + seg * 8;
  const short* Bg = Bt + (size_t)(n0 + lr) * K + seg * 8;

  auto stageA = [&](int d, int k0) {
    #pragma unroll
    for (int i = 0; i < 4; i++) {
      const int c = w * 4 + i;             // 32 chunks x 8 rows = 256 rows
      gload16(Ag + (size_t)(c * 8) * K + k0, Abase + d * TSZ + c * 512);
    }
  };
  auto stageB = [&](int d, int k0) {
    #pragma unroll
    for (int i = 0; i < 4; i++) {
      const int c = w * 4 + i;
      gload16(Bg + (size_t)(c * 8) * K + k0, Bbase + d * TSZ + c * 512);
    }
  };
  auto readA = [&](s16x8 (&dst)[4][2], int d, int qm) {
    #pragma unroll
    for (int mt = 0; mt < 4; mt++) {
      const int ar = wr * 128 + qm * 64 + mt * 16 + lm;
      #pragma unroll
      for (int ks = 0; ks < 2; ks++) {
        const int sg = (ks * 4 + lk) ^ (ar & 7);
        dst[mt][ks] = *(const s16x8*)&Abase[d * TSZ + ar * 64 + sg * 8];
      }
    }
  };
  auto readB = [&](s16x8 (&dst)[2][2], int d, int qn) {
    #pragma unroll
    for (int nt = 0; nt < 2; nt++) {
      const int br = wc * 64 + qn * 32 + nt * 16 + lm;
      #pragma unroll
      for (int ks = 0; ks < 2; ks++) {
        const int sg = (ks * 4 + lk) ^ (br & 7);
        dst[nt][ks] = *(const s16x8*)&Bbase[d * TSZ + br * 64 + sg * 8];
      }
    }
  };

  const int nk = K >> 6;
  stageA(0, 0); stageB(0, 0);
  asm volatile("s_waitcnt vmcnt(0)" ::: "memory");
  __builtin_amdgcn_sched_barrier(0);
  __builtin_amdgcn_s_barrier();

  s16x8 afA[4][2], bf0[2][2], bf1[2][2];
  for (int j = 0; j < nk; ++j) {
    const int cur = j & 1;
    const bool more = (j + 1 < nk);
    // ---- ph0: quad(0,0); read A-quad0 + B-half0; stage next A ----
    readA(afA, cur, 0);
    readB(bf0, cur, 0);
    if (more) stageA(cur ^ 1, (j + 1) << 6);
    __builtin_amdgcn_s_barrier();
    asm volatile("s_waitcnt lgkmcnt(0)" ::: "memory");
    __builtin_amdgcn_sched_barrier(0);
    __builtin_amdgcn_s_setprio(1);
    mmac<0, 0>(acc, afA, bf0);
    __builtin_amdgcn_s_setprio(0);
    __builtin_amdgcn_s_barrier();
    // ---- ph1: quad(0,1); read B-half1; stage next B ----
    readB(bf1, cur, 1);
    if (more) stageB(cur ^ 1, (j + 1) << 6);
    __builtin_amdgcn_s_barrier();
    asm volatile("s_waitcnt lgkmcnt(0)" ::: "memory");
    __builtin_amdgcn_sched_barrier(0);
    __builtin_amdgcn_s_setprio(1);
    mmac<0, 1>(acc, afA, bf1);
    __builtin_amdgcn_s_setprio(0);
    __builtin_amdgcn_s_barrier();
    // ---- ph2: quad(1,1); read A-quad1 ----
    readA(afA, cur, 1);
    __builtin_amdgcn_s_barrier();
    asm volatile("s_waitcnt lgkmcnt(0)" ::: "memory");
    __builtin_amdgcn_sched_barrier(0);
    __builtin_amdgcn_s_setprio(1);
    mmac<1, 1>(acc, afA, bf1);
    __builtin_amdgcn_s_setprio(0);
    __builtin_amdgcn_s_barrier();
    // ---- ph3: quad(1,0); no reads; boundary drain ----
    __builtin_amdgcn_s_setprio(1);
    mmac<1, 0>(acc, afA, bf0);
    __builtin_amdgcn_s_setprio(0);
    if (more) {
      asm volatile("s_waitcnt vmcnt(0)" ::: "memory");
      __builtin_amdgcn_sched_barrier(0);
    }
    __builtin_amdgcn_s_barrier();
  }

  // epilogue
  #pragma unroll
  for (int qm = 0; qm < 2; qm++) {
    #pragma unroll
    for (int qn = 0; qn < 2; qn++) {
      #pragma unroll
      for (int nt = 0; nt < 2; nt++) {
        const int col = n0 + wc * 64 + qn * 32 + nt * 16 + lm;
        if (EPI == 0) {
          const int cwhich = col >= 1536 ? 2 : (col >= 768 ? 1 : 0);
          const int cwi = col - cwhich * 768;
          const float* bsel = cwhich == 0 ? bias : (cwhich == 1 ? bias1 : bias2);
          const float bvv = bsel[cwi];
          const float sc = (cwhich == 0) ? 0.125f : 1.f;
          const int hh = cwi >> 6, dh = cwi & 63;
          short* outp = (short*)out + (size_t)cwhich * ((size_t)8192 * 768);
          #pragma unroll
          for (int mt = 0; mt < 4; mt++) {
            #pragma unroll
            for (int rr = 0; rr < 4; rr++) {
              const int row = m0 + wr * 128 + qm * 64 + mt * 16 + lk * 4 + rr;
              const int b = row >> 12, s = row & 4095;
              outp[((((size_t)b * NH + hh) * S_LEN + s) << 6) + dh] =
                  f2bf((acc[qm * 4 + mt][qn * 2 + nt][rr] + bvv) * sc);
            }
          }
        } else {
          const float bvv = bias[col];
          #pragma unroll
          for (int mt = 0; mt < 4; mt++) {
            #pragma unroll
            for (int rr = 0; rr < 4; rr++) {
              const int row = m0 + wr * 128 + qm * 64 + mt * 16 + lk * 4 + rr;
              float v = acc[qm * 4 + mt][qn * 2 + nt][rr] + bvv;
              float u = 0.7978845608f * v * (1.f + 0.044715f * v * v);
              float e = __expf(2.f * u);
              float th = 1.f - 2.f / (e + 1.f);
              ((short*)out)[(size_t)row * N + col] = f2bf(0.5f * v * (1.f + th));
            }
          }
        }
      }
    }
  }
}

// ---------------- 2-phase 128xBN GEMM (proj / FF2) --------------------------
// EPI 2: acc+bias+resid_f32 -> f32; EPI 3: acc+bias+resid_bf16 -> f32
template <int EPI, int BN>
__global__ void __launch_bounds__(256) gemm_bt(
    const short* __restrict__ A, const short* __restrict__ Bt,
    const float* __restrict__ bias, const void* __restrict__ resid,
    void* __restrict__ out, int N, int K) {
  constexpr int NT = BN / 32;
  __shared__ __align__(16) short As[2][128 * 64];
  __shared__ __align__(16) short Bs[2][BN * 64];
  const int tid = threadIdx.x;
  const int lane = tid & 63;
  const int w = tid >> 6;
  const int wr = w >> 1, wc = w & 1;
  const int m0 = blockIdx.x * 128, n0 = blockIdx.y * BN;
  const int lr = lane >> 3;
  const int seg = (lane & 7) ^ lr;
  f32x4 acc[4][NT];
  #pragma unroll
  for (int i = 0; i < 4; i++)
    #pragma unroll
    for (int j = 0; j < NT; j++) { acc[i][j][0] = 0.f; acc[i][j][1] = 0.f; acc[i][j][2] = 0.f; acc[i][j][3] = 0.f; }

  const short* Ab = A + (size_t)(m0 + lr) * K + seg * 8;
  const short* Bb = Bt + (size_t)(n0 + lr) * K + seg * 8;

  auto stage = [&](int buf, int k0) {
    #pragma unroll
    for (int i = 0; i < 4; i++) {
      const int ca = w * 4 + i;                 // 16 chunks = 128 A rows
      gload16(Ab + (size_t)(ca * 8) * K + k0, &As[buf][ca * 512]);
    }
    #pragma unroll
    for (int i = 0; i < NT; i++) {              // BN/8 chunks total (FIXED r6 bug)
      const int cb = w * NT + i;
      gload16(Bb + (size_t)(cb * 8) * K + k0, &Bs[buf][cb * 512]);
    }
  };

  const int nt_k = K >> 6;
  stage(0, 0);
  __syncthreads();
  int cur = 0;
  for (int t = 0; t < nt_k; ++t) {
    if (t + 1 < nt_k) stage(cur ^ 1, (t + 1) << 6);
    const int kc = (lane >> 4) * 8;
    #pragma unroll
    for (int ks = 0; ks < 2; ks++) {
      const int kb = ks * 32 + kc;
      s16x8 af[4], bfr[NT];
      #pragma unroll
      for (int mt = 0; mt < 4; mt++) {
        const int arow = wr * 64 + mt * 16 + (lane & 15);
        af[mt] = *(const s16x8*)&As[cur][arow * 64 + (kb ^ ((arow & 7) << 3))];
      }
      #pragma unroll
      for (int nt = 0; nt < NT; nt++) {
        const int brow = wc * (BN / 2) + nt * 16 + (lane & 15);
        bfr[nt] = *(const s16x8*)&Bs[cur][brow * 64 + (kb ^ ((brow & 7) << 3))];
      }
      #pragma unroll
      for (int mt = 0; mt < 4; mt++)
        #pragma unroll
        for (int nt = 0; nt < NT; nt++)
          acc[mt][nt] = __builtin_amdgcn_mfma_f32_16x16x32_bf16(af[mt], bfr[nt], acc[mt][nt], 0, 0, 0);
    }
    if (t + 1 < nt_k) { __syncthreads(); cur ^= 1; }
  }
  #pragma unroll
  for (int nt = 0; nt < NT; nt++) {
    const int col = n0 + wc * (BN / 2) + nt * 16 + (lane & 15);
    const float bvv = bias[col];
    #pragma unroll
    for (int mt = 0; mt < 4; mt++) {
      #pragma unroll
      for (int rr = 0; rr < 4; rr++) {
        const int row = m0 + wr * 64 + mt * 16 + (lane >> 4) * 4 + rr;
        float v = acc[mt][nt][rr] + bvv;
        if (EPI == 2) {
          ((float*)out)[(size_t)row * N + col] = v + ((const float*)resid)[(size_t)row * N + col];
        } else {
          ((float*)out)[(size_t)row * N + col] = v + bf2f(((const short*)resid)[(size_t)row * N + col]);
        }
      }
    }
  }
}

// ---------------- banded attention, one block per (chunk, b*h) --------------
__global__ void __launch_bounds__(512, 1) attn_k(
    const short* __restrict__ qh, const short* __restrict__ kh,
    const short* __restrict__ vth, const int* __restrict__ am,
    short* __restrict__ ctx) {
  extern __shared__ char smraw[];
  short* Kb = (short*)smraw;
  float* dmw = (float*)(smraw + 55296);
  short* Pb = (short*)(smraw + 56832);
  const int c = blockIdx.x;
  const int bh = blockIdx.y;
  const int b = bh / NH, hh = bh % NH;
  const int tid = threadIdx.x, lane = tid & 63, w = tid >> 6;
  const int q0 = c * 128, kw0 = q0 - 128;

  for (int ch = tid; ch < 3072; ch += 512) {
    int n = ch >> 3, seg = ch & 7;
    int kp = kw0 + n; kp = kp < 0 ? 0 : (kp > S_LEN - 1 ? S_LEN - 1 : kp);
    *(s16x8*)&Kb[n * 72 + seg * 8] = *(const s16x8*)&kh[(((size_t)bh * S_LEN + kp) << 6) + seg * 8];
  }
  for (int n = tid; n < 384; n += 512) {
    int kp = kw0 + n;
    float d;
    if (kp < 0 || kp >= S_LEN) d = -1e30f;
    else d = (am[b * S_LEN + kp] != 0) ? -10000.f : 0.f;
    dmw[n] = d;
  }
  __syncthreads();

  const short* qrow = qh + ((((size_t)bh * S_LEN) + q0 + w * 16 + (lane & 15)) << 6);
  s16x8 aq0 = *(const s16x8*)&qrow[(lane >> 4) * 8];
  s16x8 aq1 = *(const s16x8*)&qrow[32 + (lane >> 4) * 8];

  f32x4 sacc[24];
  #pragma unroll
  for (int t = 0; t < 24; t++) { sacc[t][0] = 0.f; sacc[t][1] = 0.f; sacc[t][2] = 0.f; sacc[t][3] = 0.f; }
  #pragma unroll
  for (int t = 0; t < 24; t++) {
    const short* kr = &Kb[(t * 16 + (lane & 15)) * 72 + (lane >> 4) * 8];
    s16x8 bk0 = *(const s16x8*)&kr[0];
    s16x8 bk1 = *(const s16x8*)&kr[32];
    sacc[t] = __builtin_amdgcn_mfma_f32_16x16x32_bf16(aq0, bk0, sacc[t], 0, 0, 0);
    sacc[t] = __builtin_amdgcn_mfma_f32_16x16x32_bf16(aq1, bk1, sacc[t], 0, 0, 0);
  }
  const int mbase = w * 16 + (lane >> 4) * 4;
  #pragma unroll
  for (int t = 0; t < 24; t++) {
    int n = t * 16 + (lane & 15);
    float d = dmw[n];
    #pragma unroll
    for (int r = 0; r < 4; r++) {
      int j = n - (mbase + r);
      float sv = sacc[t][r] + d;
      if (j < 0 || j > 256) sv = -1e30f;
      sacc[t][r] = sv;
    }
  }
  short* Pw = Pb + w * 16 * 392;
  #pragma unroll
  for (int r = 0; r < 4; r++) {
    float mx = -3e38f;
    #pragma unroll
    for (int t = 0; t < 24; t++) mx = fmaxf(mx, sacc[t][r]);
    #pragma unroll
    for (int d = 1; d < 16; d <<= 1) mx = fmaxf(mx, __shfl_xor(mx, d));
    float sum = 0.f;
    #pragma unroll
    for (int t = 0; t < 24; t++) { float p = __expf(sacc[t][r] - mx); sacc[t][r] = p; sum += p; }
    #pragma unroll
    for (int d = 1; d < 16; d <<= 1) sum += __shfl_xor(sum, d);
    float inv = 1.f / sum;
    #pragma unroll
    for (int t = 0; t < 24; t++)
      Pw[((lane >> 4) * 4 + r) * 392 + t * 16 + (lane & 15)] = f2bf(sacc[t][r] * inv);
  }
  __syncthreads();

  short* Vt = (short*)smraw;
  for (int ch = tid; ch < 3072; ch += 512) {
    int dh = ch / 48, seg = ch % 48;
    int n0 = seg * 8, kp0 = kw0 + n0;
    const short* vr = vth + (((size_t)bh * 64 + dh) << 12);
    s16x8 vv;
    if (kp0 >= 0 && kp0 + 7 < S_LEN) {
      vv = *(const s16x8*)&vr[kp0];
    } else {
      #pragma unroll
      for (int e = 0; e < 8; e++) {
        int kp = kp0 + e; kp = kp < 0 ? 0 : (kp > S_LEN - 1 ? S_LEN - 1 : kp);
        vv[e] = vr[kp];
      }
    }
    *(s16x8*)&Vt[dh * 392 + n0] = vv;
  }
  __syncthreads();

  f32x4 oacc[4];
  #pragma unroll
  for (int i = 0; i < 4; i++) { oacc[i][0] = 0.f; oacc[i][1] = 0.f; oacc[i][2] = 0.f; oacc[i][3] = 0.f; }
  #pragma unroll
  for (int ksp = 0; ksp < 12; ksp++) {
    s16x8 pa = *(const s16x8*)&Pw[(lane & 15) * 392 + ksp * 32 + (lane >> 4) * 8];
    #pragma unroll
    for (int ct = 0; ct < 4; ct++) {
      s16x8 vb = *(const s16x8*)&Vt[(ct * 16 + (lane & 15)) * 392 + ksp * 32 + (lane >> 4) * 8];
      oacc[ct] = __builtin_amdgcn_mfma_f32_16x16x32_bf16(pa, vb, oacc[ct], 0, 0, 0);
    }
  }
  #pragma unroll
  for (int ct = 0; ct < 4; ct++) {
    #pragma unroll
    for (int r = 0; r < 4; r++) {
      int srow = q0 + w * 16 + (lane >> 4) * 4 + r;
      int col = hh * 64 + ct * 16 + (lane & 15);
      ctx[((size_t)b * S_LEN + srow) * HIDD + col] = f2bf(oacc[ct][r]);
    }
  }
}

// ---------------- LayerNorm, one wave per row (HID=768) ---------------------
template <int OUTBF>
__global__ void ln_k(const float* __restrict__ in, const float* __restrict__ g,
                     const float* __restrict__ bb, void* __restrict__ out) {
  int row = blockIdx.x * 4 + (threadIdx.x >> 6);
  int lane = threadIdx.x & 63;
  const float4* x = (const float4*)(in + (size_t)row * HIDD);
  float4 v0 = x[lane], v1 = x[lane + 64], v2 = x[lane + 128];
  float s = v0.x + v0.y + v0.z + v0.w + v1.x + v1.y + v1.z + v1.w + v2.x + v2.y + v2.z + v2.w;
  float ss = v0.x * v0.x + v0.y * v0.y + v0.z * v0.z + v0.w * v0.w
           + v1.x * v1.x + v1.y * v1.y + v1.z * v1.z + v1.w * v1.w
           + v2.x * v2.x + v2.y * v2.y + v2.z * v2.z + v2.w * v2.w;
  #pragma unroll
  for (int d = 1; d < 64; d <<= 1) { s += __shfl_xor(s, d); ss += __shfl_xor(ss, d); }
  float mean = s * (1.f / 768.f);
  float var = ss * (1.f / 768.f) - mean * mean;
  float rs = rsqrtf(var + 1e-12f);
  const float4* gp = (const float4*)g;
  const float4* bp = (const float4*)bb;
  #pragma unroll
  for (int seg = 0; seg < 3; seg++) {
    int idx = lane + seg * 64;
    float4 vv = seg == 0 ? v0 : seg == 1 ? v1 : v2;
    float4 gg = gp[idx], b4 = bp[idx];
    float o0 = (vv.x - mean) * rs * gg.x + b4.x;
    float o1 = (vv.y - mean) * rs * gg.y + b4.y;
    float o2 = (vv.z - mean) * rs * gg.z + b4.z;
    float o3 = (vv.w - mean) * rs * gg.w + b4.w;
    if (OUTBF) {
      s16x4 o; o[0] = f2bf(o0); o[1] = f2bf(o1); o[2] = f2bf(o2); o[3] = f2bf(o3);
      ((s16x4*)out)[(size_t)row * 192 + idx] = o;
    } else {
      float4 o; o.x = o0; o.y = o1; o.z = o2; o.w = o3;
      ((float4*)out)[(size_t)row * 192 + idx] = o;
    }
  }
}

extern "C" void kernel_launch(void* const* d_in, const int* in_sizes, int n_in,
                              void* d_out, int out_size, void* d_ws, size_t ws_size,
                              hipStream_t stream) {
  const float* hid = (const float*)d_in[0];
  const int* am = (const int*)d_in[1];
  const float* Wq = (const float*)d_in[2];  const float* bq = (const float*)d_in[3];
  const float* Wk = (const float*)d_in[4];  const float* bk = (const float*)d_in[5];
  const float* Wv = (const float*)d_in[6];  const float* bv = (const float*)d_in[7];
  const float* Wd = (const float*)d_in[8];  const float* bd = (const float*)d_in[9];
  const float* g1 = (const float*)d_in[10]; const float* b1 = (const float*)d_in[11];
  const float* Wf = (const float*)d_in[12]; const float* bf = (const float*)d_in[13];
  const float* Wo = (const float*)d_in[14]; const float* bo = (const float*)d_in[15];
  const float* g2 = (const float*)d_in[16]; const float* b2 = (const float*)d_in[17];

  char* ws = (char*)d_ws;
  size_t off = 0;
  auto alloc = [&](size_t bytes) { char* p = ws + off; off += (bytes + 255) & ~(size_t)255; return p; };
  short* Xb   = (short*)alloc((size_t)8192 * 768 * 2);
  short* Wqb  = (short*)alloc((size_t)768 * 768 * 2);   // contiguous q,k,v
  short* Wkb  = (short*)alloc((size_t)768 * 768 * 2);
  short* Wvb  = (short*)alloc((size_t)768 * 768 * 2);
  short* Wdb  = (short*)alloc((size_t)768 * 768 * 2);
  short* Wfb  = (short*)alloc((size_t)3072 * 768 * 2);
  short* Wob  = (short*)alloc((size_t)768 * 3072 * 2);
  short* qh   = (short*)alloc((size_t)8192 * 768 * 2);  // contiguous q,k,v
  short* kh   = (short*)alloc((size_t)8192 * 768 * 2);
  short* vh   = (short*)alloc((size_t)8192 * 768 * 2);
  short* vth  = (short*)alloc((size_t)8192 * 768 * 2);
  short* ctx  = (short*)alloc((size_t)8192 * 768 * 2);
  short* aob  = (short*)alloc((size_t)8192 * 768 * 2);
  short* ffb  = (short*)alloc((size_t)8192 * 3072 * 2);
  float* f2r  = (float*)alloc((size_t)8192 * 768 * 4);
  float* ln1in = (float*)d_out;
  (void)vh; (void)kh;

  hipFuncSetAttribute(reinterpret_cast<const void*>(attn_k),
                      hipFuncAttributeMaxDynamicSharedMemorySize, 157184);
  hipFuncSetAttribute(reinterpret_cast<const void*>(&gemm8p<0>),
                      hipFuncAttributeMaxDynamicSharedMemorySize, 131072);
  hipFuncSetAttribute(reinterpret_cast<const void*>(&gemm8p<1>),
                      hipFuncAttributeMaxDynamicSharedMemorySize, 131072);

  convx_k<<<6144, 256, 0, stream>>>(hid, Xb);
  wtrans_k<<<1728, 256, 0, stream>>>(Wq, Wk, Wv, Wd, Wf, Wo, Wqb, Wkb, Wvb, Wdb, Wfb, Wob);

  // fused QKV: [8192][2304] = Xb * [Wqb;Wkb;Wvb]^T  (288 blocks)
  gemm8p<0><<<288, 512, 131072, stream>>>(Xb, Wqb, bq, bk, bv, qh, 2304, 768, 32);
  vtrans_k<<<dim3(64, 24), 256, 0, stream>>>(vh, vth);
  attn_k<<<dim3(32, 24), 512, 157184, stream>>>(qh, kh, vth, am, ctx);
  gemm_bt<2, 64><<<dim3(64, 12), 256, 0, stream>>>(ctx, Wdb, bd, hid, ln1in, 768, 768);
  ln_k<1><<<2048, 256, 0, stream>>>(ln1in, g1, b1, aob);
  // FF1: [8192][3072] GELU  (384 blocks)
  gemm8p<1><<<384, 512, 131072, stream>>>(aob, Wfb, bf, nullptr, nullptr, ffb, 3072, 768, 32);
  gemm_bt<3, 64><<<dim3(64, 12), 256, 0, stream>>>(ffb, Wob, bo, aob, f2r, 768, 3072);
  ln_k<0><<<2048, 256, 0, stream>>>(f2r, g2, b2, d_out);
}

// Round 8
// 256.130 us; speedup vs baseline: 1.0753x; 1.0753x over previous
//
#include <hip/hip_runtime.h>
#include <cstdint>
#include <cstddef>

#define S_LEN 4096
#define HIDD 768
#define NH 12
#define FFD 3072

typedef float f32x4 __attribute__((ext_vector_type(4)));
typedef short s16x8 __attribute__((ext_vector_type(8)));
typedef short s16x4 __attribute__((ext_vector_type(4)));

__device__ __forceinline__ short f2bf(float f) {
  unsigned u = __float_as_uint(f);
  u += 0x7fffu + ((u >> 16) & 1u);
  return (short)(u >> 16);
}
__device__ __forceinline__ float bf2f(short s) {
  return __uint_as_float(((unsigned)(unsigned short)s) << 16);
}

// async global->LDS, 16B per lane; LDS dest is wave-uniform base + lane*16
__device__ __forceinline__ void gload16(const short* g, short* l) {
  __builtin_amdgcn_global_load_lds(
      (__attribute__((address_space(1))) void*)(void*)const_cast<short*>(g),
      (__attribute__((address_space(3))) void*)l, 16, 0, 0);
}

// ------------- prep: x f32->bf16 (ids 0..6143) + weight transpose (rest) ----
__global__ void prep_k(const float* __restrict__ x, short* __restrict__ xo,
                       const float* __restrict__ Wq, const float* __restrict__ Wk,
                       const float* __restrict__ Wv, const float* __restrict__ Wd,
                       const float* __restrict__ Wf, const float* __restrict__ Wo,
                       short* __restrict__ oq, short* __restrict__ ok_,
                       short* __restrict__ ov, short* __restrict__ od,
                       short* __restrict__ of_, short* __restrict__ oo) {
  __shared__ float tl[64][65];
  int id = blockIdx.x;
  if (id < 6144) {
    size_t i = (size_t)id * 256 + threadIdx.x;
    float4 f = ((const float4*)x)[i];
    s16x4 v;
    v[0] = f2bf(f.x); v[1] = f2bf(f.y); v[2] = f2bf(f.z); v[3] = f2bf(f.w);
    ((s16x4*)xo)[i] = v;
    return;
  }
  id -= 6144;
  const float* in; short* out; int R, C, tr, tc;
  if (id < 576) {
    int wsel = id / 144; int t = id % 144; tr = t / 12; tc = t % 12; R = 768; C = 768;
    in = wsel == 0 ? Wq : wsel == 1 ? Wk : wsel == 2 ? Wv : Wd;
    out = wsel == 0 ? oq : wsel == 1 ? ok_ : wsel == 2 ? ov : od;
  } else if (id < 1152) {
    int t = id - 576; tr = t / 48; tc = t % 48; R = 768; C = 3072; in = Wf; out = of_;
  } else {
    int t = id - 1152; tr = t / 12; tc = t % 12; R = 3072; C = 768; in = Wo; out = oo;
  }
  int r0 = tr * 64, c0 = tc * 64;
  int tid = threadIdx.x;
  #pragma unroll
  for (int i = 0; i < 16; i++) {
    int idx = i * 256 + tid; int r = idx >> 6, cc = idx & 63;
    tl[r][cc] = in[(size_t)(r0 + r) * C + c0 + cc];
  }
  __syncthreads();
  #pragma unroll
  for (int i = 0; i < 16; i++) {
    int idx = i * 256 + tid; int cc = idx >> 6, rr = idx & 63;
    out[(size_t)(c0 + cc) * R + r0 + rr] = f2bf(tl[rr][cc]);
  }
}

// ---------------- generic bf16 GEMM: C[M][N] = A[M][K] * Bt[N][K]^T ---------
// 2-phase double-buffered (best-measured structure, r3/r4): stage tile t+1
// (global_load_lds w=16, pre-swizzled source) before computing tile t, one
// __syncthreads per K-step. T2 both-sides swizzle (0 conflicts, verified).
// EPI 0: fused QKV (N=2304): q/k head-split bf16; V written DIRECTLY in
//        transposed vth[bh][dh][s] layout (packed s16x4) -> no vtrans pass.
// EPI 1: tanh-GELU(acc+bias) -> bf16 row-major
// EPI 2: acc+bias+resid_f32  -> f32 row-major
// EPI 3: acc+bias+resid_bf16 -> f32 row-major
template <int EPI, int BN>
__global__ void __launch_bounds__(256) gemm_bt(
    const short* __restrict__ A, const short* __restrict__ Bt,
    const float* __restrict__ bias, const float* __restrict__ bias1,
    const float* __restrict__ bias2, const void* __restrict__ resid,
    void* __restrict__ out, int N, int K) {
  constexpr int NT = BN / 32;     // per-wave n-tiles (4 or 2)
  __shared__ __align__(16) short As[2][128 * 64];
  __shared__ __align__(16) short Bs[2][BN * 64];
  const int tid = threadIdx.x;
  const int lane = tid & 63;
  const int w = tid >> 6;
  const int wr = w >> 1, wc = w & 1;
  const int m0 = blockIdx.x * 128, n0 = blockIdx.y * BN;
  const int lr = lane >> 3;              // row within 8-row chunk
  const int seg = (lane & 7) ^ lr;       // pre-swizzled 16B segment in row
  f32x4 acc[4][NT];
  #pragma unroll
  for (int i = 0; i < 4; i++)
    #pragma unroll
    for (int j = 0; j < NT; j++) { acc[i][j][0] = 0.f; acc[i][j][1] = 0.f; acc[i][j][2] = 0.f; acc[i][j][3] = 0.f; }

  const short* Ab = A + (size_t)(m0 + lr) * K + seg * 8;
  const short* Bb = Bt + (size_t)(n0 + lr) * K + seg * 8;

  auto stage = [&](int buf, int k0) {
    #pragma unroll
    for (int i = 0; i < 4; i++) {
      const int ca = w * 4 + i;                 // 16 chunks = 128 A rows
      gload16(Ab + (size_t)(ca * 8) * K + k0, &As[buf][ca * 512]);
    }
    #pragma unroll
    for (int i = 0; i < NT; i++) {              // BN/8 chunks total
      const int cb = w * NT + i;
      gload16(Bb + (size_t)(cb * 8) * K + k0, &Bs[buf][cb * 512]);
    }
  };

  const int nt_k = K >> 6;
  stage(0, 0);
  __syncthreads();
  int cur = 0;
  for (int t = 0; t < nt_k; ++t) {
    if (t + 1 < nt_k) stage(cur ^ 1, (t + 1) << 6);
    const int kc = (lane >> 4) * 8;
    #pragma unroll
    for (int ks = 0; ks < 2; ks++) {
      const int kb = ks * 32 + kc;
      s16x8 af[4], bfr[NT];
      #pragma unroll
      for (int mt = 0; mt < 4; mt++) {
        const int arow = wr * 64 + mt * 16 + (lane & 15);
        af[mt] = *(const s16x8*)&As[cur][arow * 64 + (kb ^ ((arow & 7) << 3))];
      }
      #pragma unroll
      for (int nt = 0; nt < NT; nt++) {
        const int brow = wc * (BN / 2) + nt * 16 + (lane & 15);
        bfr[nt] = *(const s16x8*)&Bs[cur][brow * 64 + (kb ^ ((brow & 7) << 3))];
      }
      #pragma unroll
      for (int mt = 0; mt < 4; mt++)
        #pragma unroll
        for (int nt = 0; nt < NT; nt++)
          acc[mt][nt] = __builtin_amdgcn_mfma_f32_16x16x32_bf16(af[mt], bfr[nt], acc[mt][nt], 0, 0, 0);
    }
    if (t + 1 < nt_k) { __syncthreads(); cur ^= 1; }
  }
  #pragma unroll
  for (int nt = 0; nt < NT; nt++) {
    const int col = n0 + wc * (BN / 2) + nt * 16 + (lane & 15);
    if (EPI == 0) {
      const int cwhich = col >= 1536 ? 2 : (col >= 768 ? 1 : 0);
      const int cwi = col - cwhich * 768;
      const float* bsel = cwhich == 0 ? bias : (cwhich == 1 ? bias1 : bias2);
      const float bvv = bsel[cwi];
      const int hh = cwi >> 6, dh = cwi & 63;
      if (cwhich == 2) {
        // V: write transposed vth[(b*NH+hh)*64+dh][s], 4 consecutive s packed
        short* vtp = (short*)resid;
        #pragma unroll
        for (int mt = 0; mt < 4; mt++) {
          const int row = m0 + wr * 64 + mt * 16 + (lane >> 4) * 4;
          const int b = row >> 12, s = row & 4095;
          s16x4 o;
          #pragma unroll
          for (int rr = 0; rr < 4; rr++) o[rr] = f2bf(acc[mt][nt][rr] + bvv);
          *(s16x4*)&vtp[(((size_t)(b * NH + hh) * 64 + dh) << 12) + s] = o;
        }
      } else {
        const float sc = (cwhich == 0) ? 0.125f : 1.f;
        short* outp = (short*)out + (size_t)cwhich * ((size_t)8192 * 768);
        #pragma unroll
        for (int mt = 0; mt < 4; mt++) {
          #pragma unroll
          for (int rr = 0; rr < 4; rr++) {
            const int row = m0 + wr * 64 + mt * 16 + (lane >> 4) * 4 + rr;
            const int b = row >> 12, s = row & 4095;
            outp[((((size_t)b * NH + hh) * S_LEN + s) << 6) + dh] = f2bf((acc[mt][nt][rr] + bvv) * sc);
          }
        }
      }
    } else {
      const float bvv = bias[col];
      #pragma unroll
      for (int mt = 0; mt < 4; mt++) {
        #pragma unroll
        for (int rr = 0; rr < 4; rr++) {
          const int row = m0 + wr * 64 + mt * 16 + (lane >> 4) * 4 + rr;
          float v = acc[mt][nt][rr] + bvv;
          if (EPI == 1) {
            // tanh-form GELU (|err| vs erf-form ~3e-3, << bf16 quantum here)
            float u = 0.7978845608f * v * (1.f + 0.044715f * v * v);
            float e = __expf(2.f * u);
            float th = 1.f - 2.f / (e + 1.f);
            ((short*)out)[(size_t)row * N + col] = f2bf(0.5f * v * (1.f + th));
          } else if (EPI == 2) {
            ((float*)out)[(size_t)row * N + col] = v + ((const float*)resid)[(size_t)row * N + col];
          } else {
            ((float*)out)[(size_t)row * N + col] = v + bf2f(((const short*)resid)[(size_t)row * N + col]);
          }
        }
      }
    }
  }
}

// ---------------- banded attention, one block per (chunk, b*h) --------------
// LDS: Kb [384][72] bf16 (phase 1) overlaid by Vt [64][392] (phase 2),
//      dmw [384] f32, Pb 8 waves x [16][392] bf16.   total 157,184 B
__global__ void __launch_bounds__(512, 1) attn_k(
    const short* __restrict__ qh, const short* __restrict__ kh,
    const short* __restrict__ vth, const int* __restrict__ am,
    short* __restrict__ ctx) {
  extern __shared__ char smraw[];
  short* Kb = (short*)smraw;
  float* dmw = (float*)(smraw + 55296);
  short* Pb = (short*)(smraw + 56832);
  const int c = blockIdx.x;
  const int bh = blockIdx.y;
  const int b = bh / NH, hh = bh % NH;
  const int tid = threadIdx.x, lane = tid & 63, w = tid >> 6;
  const int q0 = c * 128, kw0 = q0 - 128;

  for (int ch = tid; ch < 3072; ch += 512) {
    int n = ch >> 3, seg = ch & 7;
    int kp = kw0 + n; kp = kp < 0 ? 0 : (kp > S_LEN - 1 ? S_LEN - 1 : kp);
    *(s16x8*)&Kb[n * 72 + seg * 8] = *(const s16x8*)&kh[(((size_t)bh * S_LEN + kp) << 6) + seg * 8];
  }
  for (int n = tid; n < 384; n += 512) {
    int kp = kw0 + n;
    float d;
    if (kp < 0 || kp >= S_LEN) d = -1e30f;
    else d = (am[b * S_LEN + kp] != 0) ? -10000.f : 0.f;
    dmw[n] = d;
  }
  __syncthreads();

  const short* qrow = qh + ((((size_t)bh * S_LEN) + q0 + w * 16 + (lane & 15)) << 6);
  s16x8 aq0 = *(const s16x8*)&qrow[(lane >> 4) * 8];
  s16x8 aq1 = *(const s16x8*)&qrow[32 + (lane >> 4) * 8];

  f32x4 sacc[24];
  #pragma unroll
  for (int t = 0; t < 24; t++) { sacc[t][0] = 0.f; sacc[t][1] = 0.f; sacc[t][2] = 0.f; sacc[t][3] = 0.f; }
  #pragma unroll
  for (int t = 0; t < 24; t++) {
    const short* kr = &Kb[(t * 16 + (lane & 15)) * 72 + (lane >> 4) * 8];
    s16x8 bk0 = *(const s16x8*)&kr[0];
    s16x8 bk1 = *(const s16x8*)&kr[32];
    sacc[t] = __builtin_amdgcn_mfma_f32_16x16x32_bf16(aq0, bk0, sacc[t], 0, 0, 0);
    sacc[t] = __builtin_amdgcn_mfma_f32_16x16x32_bf16(aq1, bk1, sacc[t], 0, 0, 0);
  }
  const int mbase = w * 16 + (lane >> 4) * 4;
  #pragma unroll
  for (int t = 0; t < 24; t++) {
    int n = t * 16 + (lane & 15);
    float d = dmw[n];
    #pragma unroll
    for (int r = 0; r < 4; r++) {
      int j = n - (mbase + r);
      float sv = sacc[t][r] + d;
      if (j < 0 || j > 256) sv = -1e30f;
      sacc[t][r] = sv;
    }
  }
  short* Pw = Pb + w * 16 * 392;
  #pragma unroll
  for (int r = 0; r < 4; r++) {
    float mx = -3e38f;
    #pragma unroll
    for (int t = 0; t < 24; t++) mx = fmaxf(mx, sacc[t][r]);
    #pragma unroll
    for (int d = 1; d < 16; d <<= 1) mx = fmaxf(mx, __shfl_xor(mx, d));
    float sum = 0.f;
    #pragma unroll
    for (int t = 0; t < 24; t++) { float p = __expf(sacc[t][r] - mx); sacc[t][r] = p; sum += p; }
    #pragma unroll
    for (int d = 1; d < 16; d <<= 1) sum += __shfl_xor(sum, d);
    float inv = 1.f / sum;
    #pragma unroll
    for (int t = 0; t < 24; t++)
      Pw[((lane >> 4) * 4 + r) * 392 + t * 16 + (lane & 15)] = f2bf(sacc[t][r] * inv);
  }
  __syncthreads();

  short* Vt = (short*)smraw;
  for (int ch = tid; ch < 3072; ch += 512) {
    int dh = ch / 48, seg = ch % 48;
    int n0 = seg * 8, kp0 = kw0 + n0;
    const short* vr = vth + (((size_t)bh * 64 + dh) << 12);
    s16x8 vv;
    if (kp0 >= 0 && kp0 + 7 < S_LEN) {
      vv = *(const s16x8*)&vr[kp0];
    } else {
      #pragma unroll
      for (int e = 0; e < 8; e++) {
        int kp = kp0 + e; kp = kp < 0 ? 0 : (kp > S_LEN - 1 ? S_LEN - 1 : kp);
        vv[e] = vr[kp];
      }
    }
    *(s16x8*)&Vt[dh * 392 + n0] = vv;
  }
  __syncthreads();

  f32x4 oacc[4];
  #pragma unroll
  for (int i = 0; i < 4; i++) { oacc[i][0] = 0.f; oacc[i][1] = 0.f; oacc[i][2] = 0.f; oacc[i][3] = 0.f; }
  #pragma unroll
  for (int ksp = 0; ksp < 12; ksp++) {
    s16x8 pa = *(const s16x8*)&Pw[(lane & 15) * 392 + ksp * 32 + (lane >> 4) * 8];
    #pragma unroll
    for (int ct = 0; ct < 4; ct++) {
      s16x8 vb = *(const s16x8*)&Vt[(ct * 16 + (lane & 15)) * 392 + ksp * 32 + (lane >> 4) * 8];
      oacc[ct] = __builtin_amdgcn_mfma_f32_16x16x32_bf16(pa, vb, oacc[ct], 0, 0, 0);
    }
  }
  #pragma unroll
  for (int ct = 0; ct < 4; ct++) {
    #pragma unroll
    for (int r = 0; r < 4; r++) {
      int srow = q0 + w * 16 + (lane >> 4) * 4 + r;
      int col = hh * 64 + ct * 16 + (lane & 15);
      ctx[((size_t)b * S_LEN + srow) * HIDD + col] = f2bf(oacc[ct][r]);
    }
  }
}

// ---------------- LayerNorm, one wave per row (HID=768) ---------------------
template <int OUTBF>
__global__ void ln_k(const float* __restrict__ in, const float* __restrict__ g,
                     const float* __restrict__ bb, void* __restrict__ out) {
  int row = blockIdx.x * 4 + (threadIdx.x >> 6);
  int lane = threadIdx.x & 63;
  const float4* x = (const float4*)(in + (size_t)row * HIDD);
  float4 v0 = x[lane], v1 = x[lane + 64], v2 = x[lane + 128];
  float s = v0.x + v0.y + v0.z + v0.w + v1.x + v1.y + v1.z + v1.w + v2.x + v2.y + v2.z + v2.w;
  float ss = v0.x * v0.x + v0.y * v0.y + v0.z * v0.z + v0.w * v0.w
           + v1.x * v1.x + v1.y * v1.y + v1.z * v1.z + v1.w * v1.w
           + v2.x * v2.x + v2.y * v2.y + v2.z * v2.z + v2.w * v2.w;
  #pragma unroll
  for (int d = 1; d < 64; d <<= 1) { s += __shfl_xor(s, d); ss += __shfl_xor(ss, d); }
  float mean = s * (1.f / 768.f);
  float var = ss * (1.f / 768.f) - mean * mean;
  float rs = rsqrtf(var + 1e-12f);
  const float4* gp = (const float4*)g;
  const float4* bp = (const float4*)bb;
  #pragma unroll
  for (int seg = 0; seg < 3; seg++) {
    int idx = lane + seg * 64;
    float4 vv = seg == 0 ? v0 : seg == 1 ? v1 : v2;
    float4 gg = gp[idx], b4 = bp[idx];
    float o0 = (vv.x - mean) * rs * gg.x + b4.x;
    float o1 = (vv.y - mean) * rs * gg.y + b4.y;
    float o2 = (vv.z - mean) * rs * gg.z + b4.z;
    float o3 = (vv.w - mean) * rs * gg.w + b4.w;
    if (OUTBF) {
      s16x4 o; o[0] = f2bf(o0); o[1] = f2bf(o1); o[2] = f2bf(o2); o[3] = f2bf(o3);
      ((s16x4*)out)[(size_t)row * 192 + idx] = o;
    } else {
      float4 o; o.x = o0; o.y = o1; o.z = o2; o.w = o3;
      ((float4*)out)[(size_t)row * 192 + idx] = o;
    }
  }
}

extern "C" void kernel_launch(void* const* d_in, const int* in_sizes, int n_in,
                              void* d_out, int out_size, void* d_ws, size_t ws_size,
                              hipStream_t stream) {
  const float* hid = (const float*)d_in[0];
  const int* am = (const int*)d_in[1];
  const float* Wq = (const float*)d_in[2];  const float* bq = (const float*)d_in[3];
  const float* Wk = (const float*)d_in[4];  const float* bk = (const float*)d_in[5];
  const float* Wv = (const float*)d_in[6];  const float* bv = (const float*)d_in[7];
  const float* Wd = (const float*)d_in[8];  const float* bd = (const float*)d_in[9];
  const float* g1 = (const float*)d_in[10]; const float* b1 = (const float*)d_in[11];
  const float* Wf = (const float*)d_in[12]; const float* bf = (const float*)d_in[13];
  const float* Wo = (const float*)d_in[14]; const float* bo = (const float*)d_in[15];
  const float* g2 = (const float*)d_in[16]; const float* b2 = (const float*)d_in[17];

  char* ws = (char*)d_ws;
  size_t off = 0;
  auto alloc = [&](size_t bytes) { char* p = ws + off; off += (bytes + 255) & ~(size_t)255; return p; };
  short* Xb   = (short*)alloc((size_t)8192 * 768 * 2);
  short* Wqb  = (short*)alloc((size_t)768 * 768 * 2);   // contiguous q,k,v
  short* Wkb  = (short*)alloc((size_t)768 * 768 * 2);
  short* Wvb  = (short*)alloc((size_t)768 * 768 * 2);
  short* Wdb  = (short*)alloc((size_t)768 * 768 * 2);
  short* Wfb  = (short*)alloc((size_t)3072 * 768 * 2);
  short* Wob  = (short*)alloc((size_t)768 * 3072 * 2);
  short* qh   = (short*)alloc((size_t)8192 * 768 * 2);  // contiguous q,k
  short* kh   = (short*)alloc((size_t)8192 * 768 * 2);
  short* vth  = (short*)alloc((size_t)8192 * 768 * 2);  // transposed V (direct)
  short* ctx  = (short*)alloc((size_t)8192 * 768 * 2);
  short* aob  = (short*)alloc((size_t)8192 * 768 * 2);
  short* ffb  = (short*)alloc((size_t)8192 * 3072 * 2);
  float* f2r  = (float*)alloc((size_t)8192 * 768 * 4);
  float* ln1in = (float*)d_out;
  (void)kh;

  hipFuncSetAttribute(reinterpret_cast<const void*>(attn_k),
                      hipFuncAttributeMaxDynamicSharedMemorySize, 157184);

  prep_k<<<7872, 256, 0, stream>>>(hid, Xb, Wq, Wk, Wv, Wd, Wf, Wo,
                                   Wqb, Wkb, Wvb, Wdb, Wfb, Wob);

  // fused QKV: [8192][2304] = Xb * [Wqb;Wkb;Wvb]^T; q/k head-split to qh/kh,
  // v written transposed directly to vth (resid param carries vth)
  gemm_bt<0, 128><<<dim3(64, 18), 256, 0, stream>>>(Xb, Wqb, bq, bk, bv, vth, qh, 2304, 768);
  attn_k<<<dim3(32, 24), 512, 157184, stream>>>(qh, kh, vth, am, ctx);
  gemm_bt<2, 64><<<dim3(64, 12), 256, 0, stream>>>(ctx, Wdb, bd, nullptr, nullptr, hid, ln1in, 768, 768);
  ln_k<1><<<2048, 256, 0, stream>>>(ln1in, g1, b1, aob);
  gemm_bt<1, 128><<<dim3(64, 24), 256, 0, stream>>>(aob, Wfb, bf, nullptr, nullptr, nullptr, ffb, 3072, 768);
  gemm_bt<3, 64><<<dim3(64, 12), 256, 0, stream>>>(ffb, Wob, bo, nullptr, nullptr, aob, f2r, 768, 3072);
  ln_k<0><<<2048, 256, 0, stream>>>(f2r, g2, b2, d_out);
}